// Round 2
// baseline (10957.430 us; speedup 1.0000x reference)
//
#include <hip/hip_runtime.h>

constexpr int NB = 128;   // batch
constexpr int NT = 512;   // time
constexpr int ND = 64;    // input dim
constexpr int NH = 512;   // hidden
constexpr int NL = 256;   // latent

typedef _Float16 half8 __attribute__((ext_vector_type(8)));
typedef float F4 __attribute__((ext_vector_type(4)));

// ---------------- workspace layout (bytes) ----------------
constexpr size_t OFF_WFE = 0;                          // 2 MB  fragment-major W_hh_e fp16
constexpr size_t OFF_WFD = (2u << 20);                 // 2 MB  fragment-major W_hh_d fp16
constexpr size_t OFF_WFX = (4u << 20);                 // 256 KB fragment-major W_ih_e fp16
constexpr size_t OFF_WFO = (4u << 20) + (256u << 10);  // 64 KB fragment-major W_out fp16
constexpr size_t OFF_XF  = (4u << 20) + (320u << 10);  // 8 MB  x in A-fragment layout fp16
constexpr size_t OFF_HBE = OFF_XF + (8u << 20);        // 2 x 128 KB encoder h ping-pong (fp16 fragments)
constexpr size_t OFF_HBD = OFF_HBE + (256u << 10);     // 2 x 128 KB decoder h ping-pong
constexpr size_t OFF_Z   = OFF_HBD + (256u << 10);     // 128 KB z fp32
constexpr size_t OFF_ZX  = OFF_Z + (128u << 10);       // 1 MB zx fp32
constexpr size_t OFF_CNT = OFF_ZX + (1u << 20);        // 16 KB cntE + 16 KB cntD
// total ~14.0 MB

__device__ inline float sigm(float x) {
  float e = __expf(-fabsf(x));
  float p = 1.f / (1.f + e);
  return x >= 0.f ? p : 1.f - p;
}
__device__ inline float tanh_(float x) {
  float e = __expf(-2.f * fabsf(x));
  float t = (1.f - e) / (1.f + e);
  return x >= 0.f ? t : -t;
}
__device__ inline half8 cvt8(F4 a, F4 b) {
  half8 h;
  h[0] = (_Float16)a[0]; h[1] = (_Float16)a[1]; h[2] = (_Float16)a[2]; h[3] = (_Float16)a[3];
  h[4] = (_Float16)b[0]; h[5] = (_Float16)b[1]; h[6] = (_Float16)b[2]; h[7] = (_Float16)b[3];
  return h;
}

// ------- setup: gather weights + x into fragment-major fp16 layouts -------
__global__ __launch_bounds__(256) void setup_kernel(
    const float* __restrict__ x, const float* __restrict__ W_hh_e,
    const float* __restrict__ W_ih_e, const float* __restrict__ W_hh_d,
    const float* __restrict__ W_out,
    half8* __restrict__ WfE, half8* __restrict__ WfX, half8* __restrict__ WfD,
    half8* __restrict__ WfO, half8* __restrict__ Xf) {
  int c = blockIdx.x * 256 + threadIdx.x;
  if (c < 131072) {  // WfE
    int hc = c >> 12, g = (c >> 10) & 3, tt = (c >> 6) & 15, l = c & 63;
    int col = g * 512 + hc * 16 + (l & 15);
    int k8 = 4 * tt + (l >> 4);
    const F4* s = (const F4*)(W_hh_e + (size_t)col * 512 + k8 * 8);
    WfE[c] = cvt8(s[0], s[1]);
  } else if (c < 147456) {  // WfX
    int id = c - 131072;
    int hc = id >> 9, g = (id >> 7) & 3, tx = (id >> 6) & 1, l = id & 63;
    int col = g * 512 + hc * 16 + (l & 15);
    int k8 = 4 * tx + (l >> 4);
    const F4* s = (const F4*)(W_ih_e + (size_t)col * 64 + k8 * 8);
    WfX[id] = cvt8(s[0], s[1]);
  } else if (c < 278528) {  // WfD
    int id = c - 147456;
    int hc = id >> 12, g = (id >> 10) & 3, tt = (id >> 6) & 15, l = id & 63;
    int col = g * 512 + hc * 16 + (l & 15);
    int k8 = 4 * tt + (l >> 4);
    const F4* s = (const F4*)(W_hh_d + (size_t)col * 512 + k8 * 8);
    WfD[id] = cvt8(s[0], s[1]);
  } else if (c < 282624) {  // WfO
    int id = c - 278528;
    int dt = id >> 10, k = (id >> 6) & 15, l = id & 63;
    int d = dt * 16 + (l & 15);
    int k8 = k * 4 + (l >> 4);
    const F4* s = (const F4*)(W_out + (size_t)d * 512 + k8 * 8);
    WfO[id] = cvt8(s[0], s[1]);
  } else {  // Xf
    int id = c - 282624;
    int t = id >> 10, bi = (id >> 7) & 7, k8 = (id >> 4) & 7, row = id & 15;
    const F4* s = (const F4*)(x + ((size_t)(bi * 16 + row) * NT + t) * ND + k8 * 8);
    Xf[id] = cvt8(s[0], s[1]);
  }
}

// ------------------------- persistent encoder -------------------------
// 256 WGs: team bi = blockIdx&7 (XCD-local if round-robin), w = blockIdx>>3 owns hcols [16w,16w+16)
__global__ __launch_bounds__(256, 1) void enc_persist(
    const half8* __restrict__ Wf, const half8* __restrict__ Wfx,
    const half8* __restrict__ Xf, _Float16* __restrict__ Hb,
    const float* __restrict__ b_e, const int* __restrict__ lengths,
    unsigned int* __restrict__ cnt) {
  const int tid = threadIdx.x;
  const int l = tid & 63, g = tid >> 6;
  const int bi = (int)blockIdx.x & 7, w = (int)blockIdx.x >> 3;
  __shared__ float gl[4][16][17];
  __shared__ _Float16 hst[16][16];

  half8 wb[16];
  {
    const half8* Bp = Wf + (size_t)((w * 4 + g) * 16) * 64 + l;
#pragma unroll
    for (int k = 0; k < 16; k++) wb[k] = Bp[64 * k];
  }
  const half8 wx0 = Wfx[((w * 4 + g) * 2 + 0) * 64 + l];
  const half8 wx1 = Wfx[((w * 4 + g) * 2 + 1) * 64 + l];

  const int row = tid >> 4, col = tid & 15;
  const int b = bi * 16 + row, hcol = w * 16 + col;
  const int len = lengths[b];
  const float be0 = b_e[hcol], be1 = b_e[512 + hcol];
  const float be2 = b_e[1024 + hcol], be3 = b_e[1536 + hcol];
  float cst = 0.f, hreg = 0.f;
  unsigned int* mycnt = cnt + bi * NT;
  half8* HbW = (half8*)Hb;  // 2 bufs x 8192 chunks

  for (int t = 0; t < NT; t++) {
    if (t > 0) {
      if (tid == 0) {
        while (__hip_atomic_load(&mycnt[t - 1], __ATOMIC_RELAXED,
                                 __HIP_MEMORY_SCOPE_AGENT) < 32u)
          __builtin_amdgcn_s_sleep(1);
        __threadfence();  // acquire: invalidate stale L1/L2 before h loads
      }
      __syncthreads();
    }
    const half8* Ar = HbW + (size_t)(t & 1) * 8192 + bi * 1024 + l;
    half8 xa0 = Xf[((size_t)t * 8 + bi) * 128 + l];
    half8 xa1 = Xf[((size_t)t * 8 + bi) * 128 + 64 + l];
    F4 acc0 = {0.f, 0.f, 0.f, 0.f}, acc1 = {0.f, 0.f, 0.f, 0.f};
#pragma unroll
    for (int k = 0; k < 16; k += 2) {
      acc0 = __builtin_amdgcn_mfma_f32_16x16x32_f16(Ar[64 * k], wb[k], acc0, 0, 0, 0);
      acc1 = __builtin_amdgcn_mfma_f32_16x16x32_f16(Ar[64 * (k + 1)], wb[k + 1], acc1, 0, 0, 0);
    }
    acc0 = __builtin_amdgcn_mfma_f32_16x16x32_f16(xa0, wx0, acc0, 0, 0, 0);
    acc1 = __builtin_amdgcn_mfma_f32_16x16x32_f16(xa1, wx1, acc1, 0, 0, 0);
    F4 acc = acc0 + acc1;
    int r0 = (l >> 4) * 4;
#pragma unroll
    for (int r = 0; r < 4; r++) gl[g][r0 + r][l & 15] = acc[r];
    __syncthreads();

    float hv;
    if (t < len) {
      float gi = gl[0][row][col] + be0;
      float gf = gl[1][row][col] + be1;
      float gg = gl[2][row][col] + be2;
      float go = gl[3][row][col] + be3;
      float i = sigm(gi), f = sigm(gf), gz = tanh_(gg), o = sigm(go);
      cst = f * cst + i * gz;
      hv = o * tanh_(cst);
    } else {
      hv = hreg;
    }
    hreg = hv;
    hst[row][col] = (_Float16)hv;
    __syncthreads();

    if (tid < 64) {  // wave 0 publishes + releases
      if (tid < 32) {
        int k8 = 2 * w + (tid >> 4), r2 = tid & 15;
        half8 v = *(const half8*)&hst[r2][(tid >> 4) * 8];
        HbW[(size_t)((t + 1) & 1) * 8192 + (size_t)(bi * 64 + k8) * 16 + r2] = v;
      }
      __threadfence();  // release: drain + writeback before counter bump
      if (tid == 0) atomicAdd(&mycnt[t], 1u);
    }
  }
}

// ------------------------- z / zx -------------------------
__global__ __launch_bounds__(256) void z_kernel(const _Float16* __restrict__ Hfin,
                                                const float* __restrict__ W_lat,
                                                const float* __restrict__ b_lat,
                                                float* __restrict__ Z) {
  int b = blockIdx.x;
  int lc = threadIdx.x;
  int bi = b >> 4, row = b & 15;
  const half8* hp = (const half8*)Hfin + bi * 1024 + row;
  const F4* wp = (const F4*)(W_lat + (size_t)lc * 512);
  float acc = 0.f;
  for (int k8 = 0; k8 < 64; k8++) {
    half8 hv = hp[k8 * 16];
    F4 w0 = wp[2 * k8], w1 = wp[2 * k8 + 1];
    acc += (float)hv[0] * w0[0] + (float)hv[1] * w0[1] + (float)hv[2] * w0[2] + (float)hv[3] * w0[3]
         + (float)hv[4] * w1[0] + (float)hv[5] * w1[1] + (float)hv[6] * w1[2] + (float)hv[7] * w1[3];
  }
  Z[(size_t)b * 256 + lc] = acc + b_lat[lc];
}

__global__ __launch_bounds__(256) void zx_kernel(const float* __restrict__ Z,
                                                 const float* __restrict__ W_ihd,
                                                 const float* __restrict__ b_d,
                                                 float* __restrict__ ZX) {
  int o = blockIdx.x * 256 + threadIdx.x;
  int b = o >> 11, gc = o & 2047;
  const F4* zp = (const F4*)(Z + (size_t)b * 256);
  const F4* wp = (const F4*)(W_ihd + (size_t)gc * 256);
  float acc = 0.f;
  for (int k4 = 0; k4 < 64; k4++) {
    F4 z = zp[k4], w = wp[k4];
    acc += z[0] * w[0] + z[1] * w[1] + z[2] * w[2] + z[3] * w[3];
  }
  ZX[o] = acc + b_d[gc];
}

// ------------------------- persistent decoder -------------------------
#define OUT_PROJ(TCUR, HA)                                                       \
  {                                                                              \
    bool ma = ((TCUR) < lenA);                                                   \
    F4 oa0 = {0.f, 0.f, 0.f, 0.f}, oa1 = {0.f, 0.f, 0.f, 0.f};                   \
    _Pragma("unroll")                                                            \
    for (int k = 0; k < 16; k += 2) {                                            \
      half8 ya0 = ma ? HA[k] : half8{};                                          \
      half8 ya1 = ma ? HA[k + 1] : half8{};                                      \
      oa0 = __builtin_amdgcn_mfma_f32_16x16x32_f16(ya0, wo[k], oa0, 0, 0, 0);    \
      oa1 = __builtin_amdgcn_mfma_f32_16x16x32_f16(ya1, wo[k + 1], oa1, 0, 0, 0);\
    }                                                                            \
    F4 oa = oa0 + oa1;                                                           \
    int orow = (l >> 4) * 4;                                                     \
    _Pragma("unroll")                                                            \
    for (int r = 0; r < 4; r++) {                                                \
      int bb = bi * 16 + orow + r;                                               \
      out[((size_t)bb * NT + (TCUR)) * 64 + g * 16 + (l & 15)] = oa[r] + bo;     \
    }                                                                            \
  }

__global__ __launch_bounds__(256, 1) void dec_persist(
    const half8* __restrict__ Wf, _Float16* __restrict__ Hb,
    const float* __restrict__ ZX, const half8* __restrict__ WfO,
    const float* __restrict__ b_out, float* __restrict__ out,
    const int* __restrict__ lengths, unsigned int* __restrict__ cnt) {
  const int tid = threadIdx.x;
  const int l = tid & 63, g = tid >> 6;
  const int bi = (int)blockIdx.x & 7, w = (int)blockIdx.x >> 3;
  __shared__ float gl[4][16][17];
  __shared__ _Float16 hst[16][16];

  half8 wb[16], wo[16];
  {
    const half8* Bp = Wf + (size_t)((w * 4 + g) * 16) * 64 + l;
    const half8* Op = WfO + (size_t)(g * 16) * 64 + l;
#pragma unroll
    for (int k = 0; k < 16; k++) { wb[k] = Bp[64 * k]; wo[k] = Op[64 * k]; }
  }

  const int row = tid >> 4, col = tid & 15;
  const int b = bi * 16 + row, hcol = w * 16 + col;
  const int len = lengths[b];
  const int lenA = lengths[bi * 16 + (l & 15)];  // mask for A-rows (lane-indexed)
  const float bo = b_out[g * 16 + (l & 15)];
  const float zr0 = ZX[(size_t)b * 2048 + hcol];
  const float zr1 = ZX[(size_t)b * 2048 + 512 + hcol];
  const float zr2 = ZX[(size_t)b * 2048 + 1024 + hcol];
  const float zr3 = ZX[(size_t)b * 2048 + 1536 + hcol];
  float cst = 0.f, hreg = 0.f;
  unsigned int* mycnt = cnt + bi * NT;
  half8* HbW = (half8*)Hb;

  for (int t = 0; t < NT; t++) {
    if (t > 0) {
      if (tid == 0) {
        while (__hip_atomic_load(&mycnt[t - 1], __ATOMIC_RELAXED,
                                 __HIP_MEMORY_SCOPE_AGENT) < 32u)
          __builtin_amdgcn_s_sleep(1);
        __threadfence();
      }
      __syncthreads();
    }
    const half8* Ar = HbW + (size_t)(t & 1) * 8192 + bi * 1024 + l;
    half8 ha[16];
#pragma unroll
    for (int k = 0; k < 16; k++) ha[k] = Ar[64 * k];
    F4 acc0 = {0.f, 0.f, 0.f, 0.f}, acc1 = {0.f, 0.f, 0.f, 0.f};
#pragma unroll
    for (int k = 0; k < 16; k += 2) {
      acc0 = __builtin_amdgcn_mfma_f32_16x16x32_f16(ha[k], wb[k], acc0, 0, 0, 0);
      acc1 = __builtin_amdgcn_mfma_f32_16x16x32_f16(ha[k + 1], wb[k + 1], acc1, 0, 0, 0);
    }
    F4 acc = acc0 + acc1;
    int r0 = (l >> 4) * 4;
#pragma unroll
    for (int r = 0; r < 4; r++) gl[g][r0 + r][l & 15] = acc[r];
    __syncthreads();

    float hv;
    if (t < len) {
      float gi = gl[0][row][col] + zr0;
      float gf = gl[1][row][col] + zr1;
      float gg = gl[2][row][col] + zr2;
      float go = gl[3][row][col] + zr3;
      float i = sigm(gi), f = sigm(gf), gz = tanh_(gg), o = sigm(go);
      cst = f * cst + i * gz;
      hv = o * tanh_(cst);
    } else {
      hv = hreg;
    }
    hreg = hv;
    hst[row][col] = (_Float16)hv;
    __syncthreads();

    if (tid < 64) {
      if (tid < 32) {
        int k8 = 2 * w + (tid >> 4), r2 = tid & 15;
        half8 v = *(const half8*)&hst[r2][(tid >> 4) * 8];
        HbW[(size_t)((t + 1) & 1) * 8192 + (size_t)(bi * 64 + k8) * 16 + r2] = v;
      }
      __threadfence();
      if (tid == 0) atomicAdd(&mycnt[t], 1u);
    }

    // fused output projection for time t-1 (hidden behind the team barrier)
    if (((t & 31) == w) && t > 0) OUT_PROJ(t - 1, ha);
  }

  // tail: out row for t = 511 from final h (buf 0)
  if (w == 31) {
    if (tid == 0) {
      while (__hip_atomic_load(&mycnt[NT - 1], __ATOMIC_RELAXED,
                               __HIP_MEMORY_SCOPE_AGENT) < 32u)
        __builtin_amdgcn_s_sleep(1);
      __threadfence();
    }
    __syncthreads();
    const half8* Ar = HbW + bi * 1024 + l;  // (NT&1)==0
    half8 ha[16];
#pragma unroll
    for (int k = 0; k < 16; k++) ha[k] = Ar[64 * k];
    OUT_PROJ(NT - 1, ha);
  }
}

// ------------------------- host -------------------------
extern "C" void kernel_launch(void* const* d_in, const int* in_sizes, int n_in,
                              void* d_out, int out_size, void* d_ws, size_t ws_size,
                              hipStream_t stream) {
  const float* x      = (const float*)d_in[0];
  const int* lengths  = (const int*)d_in[1];
  const float* W_ih_e = (const float*)d_in[2];
  const float* W_hh_e = (const float*)d_in[3];
  const float* b_e    = (const float*)d_in[4];
  const float* W_lat  = (const float*)d_in[5];
  const float* b_lat  = (const float*)d_in[6];
  const float* W_ih_d = (const float*)d_in[7];
  const float* W_hh_d = (const float*)d_in[8];
  const float* b_d    = (const float*)d_in[9];
  const float* W_out  = (const float*)d_in[10];
  const float* b_out  = (const float*)d_in[11];
  float* out = (float*)d_out;
  char* ws = (char*)d_ws;

  half8* WfE = (half8*)(ws + OFF_WFE);
  half8* WfD = (half8*)(ws + OFF_WFD);
  half8* WfX = (half8*)(ws + OFF_WFX);
  half8* WfO = (half8*)(ws + OFF_WFO);
  half8* Xf  = (half8*)(ws + OFF_XF);
  _Float16* HbE = (_Float16*)(ws + OFF_HBE);
  _Float16* HbD = (_Float16*)(ws + OFF_HBD);
  float* Z  = (float*)(ws + OFF_Z);
  float* ZX = (float*)(ws + OFF_ZX);
  unsigned int* cntE = (unsigned int*)(ws + OFF_CNT);
  unsigned int* cntD = cntE + 8 * NT;

  hipMemsetAsync(HbE, 0, 128u << 10, stream);       // h0 = 0 (buf 0)
  hipMemsetAsync(HbD, 0, 128u << 10, stream);
  hipMemsetAsync(cntE, 0, 32u << 10, stream);       // cntE + cntD
  setup_kernel<<<3152, 256, 0, stream>>>(x, W_hh_e, W_ih_e, W_hh_d, W_out,
                                         WfE, WfX, WfD, WfO, Xf);

  enc_persist<<<256, 256, 0, stream>>>(WfE, WfX, Xf, HbE, b_e, lengths, cntE);
  z_kernel<<<128, 256, 0, stream>>>(HbE, W_lat, b_lat, Z);
  zx_kernel<<<1024, 256, 0, stream>>>(Z, W_ih_d, b_d, ZX);
  dec_persist<<<256, 256, 0, stream>>>(WfD, HbD, ZX, WfO, b_out, out, lengths, cntD);
}

// Round 3
// 3945.753 us; speedup vs baseline: 2.7770x; 2.7770x over previous
//
#include <hip/hip_runtime.h>
#include <cstdint>

constexpr int NB = 128;   // batch
constexpr int NT = 512;   // time
constexpr int ND = 64;    // input dim
constexpr int NH = 512;   // hidden
constexpr int NL = 256;   // latent

typedef _Float16 half8 __attribute__((ext_vector_type(8)));
typedef float F4 __attribute__((ext_vector_type(4)));
typedef uint32_t u32;
typedef unsigned long long u64;
typedef uint32_t u32x4 __attribute__((ext_vector_type(4)));

// ---------------- workspace layout (bytes) ----------------
constexpr size_t OFF_WFE = 0;                          // 2 MB fragment-major W_hh_e fp16
constexpr size_t OFF_WFD = (2u << 20);                 // 2 MB fragment-major W_hh_d fp16
constexpr size_t OFF_WFX = (4u << 20);                 // 256 KB fragment-major W_ih_e fp16
constexpr size_t OFF_WFO = (4u << 20) + (256u << 10);  // 64 KB fragment-major W_out fp16
constexpr size_t OFF_XF  = (4u << 20) + (320u << 10);  // 8 MB x in A-fragment layout fp16
constexpr size_t OFF_RE  = (12u << 20) + (320u << 10); // 1 MB encoder ring [8][4][16][256] u64
constexpr size_t OFF_RD  = (13u << 20) + (320u << 10); // 1 MB decoder ring
constexpr size_t OFF_Z   = (14u << 20) + (320u << 10); // 128 KB z fp32
constexpr size_t OFF_ZX  = (14u << 20) + (448u << 10); // 1 MB zx fp32
// total ~15.4 MB

__device__ inline float sigm(float x) {
  float e = __expf(-fabsf(x));
  float p = 1.f / (1.f + e);
  return x >= 0.f ? p : 1.f - p;
}
__device__ inline float tanh_(float x) {
  float e = __expf(-2.f * fabsf(x));
  float t = (1.f - e) / (1.f + e);
  return x >= 0.f ? t : -t;
}
__device__ inline half8 cvt8(F4 a, F4 b) {
  half8 h;
  h[0] = (_Float16)a[0]; h[1] = (_Float16)a[1]; h[2] = (_Float16)a[2]; h[3] = (_Float16)a[3];
  h[4] = (_Float16)b[0]; h[5] = (_Float16)b[1]; h[6] = (_Float16)b[2]; h[7] = (_Float16)b[3];
  return h;
}

// ------- setup: gather weights + x into fragment-major fp16 layouts -------
__global__ __launch_bounds__(256) void setup_kernel(
    const float* __restrict__ x, const float* __restrict__ W_hh_e,
    const float* __restrict__ W_ih_e, const float* __restrict__ W_hh_d,
    const float* __restrict__ W_out,
    half8* __restrict__ WfE, half8* __restrict__ WfX, half8* __restrict__ WfD,
    half8* __restrict__ WfO, half8* __restrict__ Xf) {
  int c = blockIdx.x * 256 + threadIdx.x;
  if (c < 131072) {  // WfE
    int hc = c >> 12, g = (c >> 10) & 3, tt = (c >> 6) & 15, l = c & 63;
    int col = g * 512 + hc * 16 + (l & 15);
    int k8 = 4 * tt + (l >> 4);
    const F4* s = (const F4*)(W_hh_e + (size_t)col * 512 + k8 * 8);
    WfE[c] = cvt8(s[0], s[1]);
  } else if (c < 147456) {  // WfX
    int id = c - 131072;
    int hc = id >> 9, g = (id >> 7) & 3, tx = (id >> 6) & 1, l = id & 63;
    int col = g * 512 + hc * 16 + (l & 15);
    int k8 = 4 * tx + (l >> 4);
    const F4* s = (const F4*)(W_ih_e + (size_t)col * 64 + k8 * 8);
    WfX[id] = cvt8(s[0], s[1]);
  } else if (c < 278528) {  // WfD
    int id = c - 147456;
    int hc = id >> 12, g = (id >> 10) & 3, tt = (id >> 6) & 15, l = id & 63;
    int col = g * 512 + hc * 16 + (l & 15);
    int k8 = 4 * tt + (l >> 4);
    const F4* s = (const F4*)(W_hh_d + (size_t)col * 512 + k8 * 8);
    WfD[id] = cvt8(s[0], s[1]);
  } else if (c < 282624) {  // WfO
    int id = c - 278528;
    int dt = id >> 10, k = (id >> 6) & 15, l = id & 63;
    int d = dt * 16 + (l & 15);
    int k8 = k * 4 + (l >> 4);
    const F4* s = (const F4*)(W_out + (size_t)d * 512 + k8 * 8);
    WfO[id] = cvt8(s[0], s[1]);
  } else {  // Xf
    int id = c - 282624;
    int t = id >> 10, bi = (id >> 7) & 7, k8 = (id >> 4) & 7, row = id & 15;
    const F4* s = (const F4*)(x + ((size_t)(bi * 16 + row) * NT + t) * ND + k8 * 8);
    Xf[id] = cvt8(s[0], s[1]);
  }
}

#define PIN4(v) asm volatile("" : "+v"(v.x), "+v"(v.y), "+v"(v.z), "+v"(v.w))

// stage h^t (tag t) from ring slot t&3 into swizzled Hlds; 1 chunk-set per thread
#define STAGE_H(RINGT, TAG)                                                      \
  {                                                                              \
    const u64* bp = (RINGT) + ((size_t)((TAG) & 3) * 16 + srow) * 256;           \
    u64 v[16];                                                                   \
    for (;;) {                                                                   \
      _Pragma("unroll")                                                          \
      for (int j = 0; j < 16; j++)                                               \
        v[j] = __hip_atomic_load(bp + (scb + 16 * (j >> 2)) * 4 + (j & 3),       \
                                 __ATOMIC_RELAXED, __HIP_MEMORY_SCOPE_AGENT);    \
      bool ok = true;                                                            \
      _Pragma("unroll")                                                          \
      for (int j = 0; j < 16; j++) ok &= ((u32)(v[j] >> 32) == (u32)(TAG));      \
      if (ok) break;                                                             \
      __builtin_amdgcn_s_sleep(1);                                               \
    }                                                                            \
    _Pragma("unroll")                                                            \
    for (int j = 0; j < 4; j++) {                                                \
      int cc = scb + 16 * j;                                                     \
      u32x4 u = {(u32)v[4 * j], (u32)v[4 * j + 1], (u32)v[4 * j + 2],            \
                 (u32)v[4 * j + 3]};                                             \
      Hlds[srow * 64 + (cc ^ (srow & 7))] = u;                                   \
    }                                                                            \
  }

// ------------------------- persistent encoder -------------------------
__global__ __launch_bounds__(256, 1) void enc_persist(
    const uint4* __restrict__ Wf, const uint4* __restrict__ Wfx,
    const uint4* __restrict__ Xf, u64* __restrict__ Ring,
    const float* __restrict__ b_e, const int* __restrict__ lengths) {
  const int tid = threadIdx.x;
  const int l = tid & 63, g = tid >> 6;
  const int bi = (int)blockIdx.x & 7, w = (int)blockIdx.x >> 3;
  __shared__ u32x4 Hlds[1024];               // 16 KB staged h (swizzled)
  __shared__ float gl[4][16][17];
  __shared__ unsigned short hst[16][16];

  uint4 wb[16];
#pragma unroll
  for (int k = 0; k < 16; k++) {
    wb[k] = Wf[(size_t)w * 4096 + (g * 16 + k) * 64 + l];
    PIN4(wb[k]);
  }
  uint4 wx0 = Wfx[(size_t)w * 512 + (g * 2 + 0) * 64 + l];
  uint4 wx1 = Wfx[(size_t)w * 512 + (g * 2 + 1) * 64 + l];
  PIN4(wx0); PIN4(wx1);

  const int row = tid >> 4, col = tid & 15;
  const int b = bi * 16 + row;
  const int len = lengths[b];
  const float be0 = b_e[w * 16 + col], be1 = b_e[512 + w * 16 + col];
  const float be2 = b_e[1024 + w * 16 + col], be3 = b_e[1536 + w * 16 + col];
  float cst = 0.f, hreg = 0.f;
  const int srow = tid >> 4, scb = tid & 15;
  u64* ringT = Ring + (size_t)bi * (4 * 16 * 256);
  const int ar = l & 15, swz = ar & 7, r0 = (l >> 4) * 4;

  for (int t = 0; t < NT; t++) {
    if (t > 0) {
      STAGE_H(ringT, t);
      __syncthreads();
    }
    F4 acc0 = {0.f, 0.f, 0.f, 0.f}, acc1 = {0.f, 0.f, 0.f, 0.f};
    if (t > 0) {
#pragma unroll
      for (int k = 0; k < 16; k += 2) {
        u32x4 a0 = Hlds[ar * 64 + (((l >> 4) + 4 * k) ^ swz)];
        u32x4 a1 = Hlds[ar * 64 + (((l >> 4) + 4 * (k + 1)) ^ swz)];
        acc0 = __builtin_amdgcn_mfma_f32_16x16x32_f16(
            __builtin_bit_cast(half8, a0), __builtin_bit_cast(half8, wb[k]), acc0, 0, 0, 0);
        acc1 = __builtin_amdgcn_mfma_f32_16x16x32_f16(
            __builtin_bit_cast(half8, a1), __builtin_bit_cast(half8, wb[k + 1]), acc1, 0, 0, 0);
      }
    }
    uint4 xa0 = Xf[((size_t)t * 8 + bi) * 128 + l];
    uint4 xa1 = Xf[((size_t)t * 8 + bi) * 128 + 64 + l];
    acc0 = __builtin_amdgcn_mfma_f32_16x16x32_f16(
        __builtin_bit_cast(half8, xa0), __builtin_bit_cast(half8, wx0), acc0, 0, 0, 0);
    acc1 = __builtin_amdgcn_mfma_f32_16x16x32_f16(
        __builtin_bit_cast(half8, xa1), __builtin_bit_cast(half8, wx1), acc1, 0, 0, 0);
    F4 acc = acc0 + acc1;
#pragma unroll
    for (int r = 0; r < 4; r++) gl[g][r0 + r][ar] = acc[r];
    __syncthreads();

    float hv;
    if (t < len) {
      float gi = gl[0][row][col] + be0;
      float gf = gl[1][row][col] + be1;
      float gg = gl[2][row][col] + be2;
      float go = gl[3][row][col] + be3;
      float i = sigm(gi), f = sigm(gf), gz = tanh_(gg), o = sigm(go);
      cst = f * cst + i * gz;
      hv = o * tanh_(cst);
    } else {
      hv = hreg;
    }
    hreg = hv;
    hst[row][col] = __builtin_bit_cast(unsigned short, (_Float16)hv);
    __syncthreads();

    if (tid < 128) {
      int pr = tid >> 3, pk = tid & 7;
      u32 lo = (u32)hst[pr][2 * pk] | ((u32)hst[pr][2 * pk + 1] << 16);
      u64 vv = ((u64)(u32)(t + 1) << 32) | lo;
      __hip_atomic_store(ringT + ((size_t)((t + 1) & 3) * 16 + pr) * 256 + w * 8 + pk,
                         vv, __ATOMIC_RELAXED, __HIP_MEMORY_SCOPE_AGENT);
    }
  }
}

// ------------------------- z / zx -------------------------
__global__ __launch_bounds__(256) void z_kernel(const u64* __restrict__ RingE,
                                                const float* __restrict__ W_lat,
                                                const float* __restrict__ b_lat,
                                                float* __restrict__ Z) {
  int b = blockIdx.x, lc = threadIdx.x;
  int bi = b >> 4, row = b & 15;
  const u64* hp = RingE + ((size_t)(bi * 4 + (NT & 3)) * 16 + row) * 256;
  float acc = 0.f;
  for (int j = 0; j < 256; j++) {
    u32 lo = (u32)hp[j];
    float h0 = (float)__builtin_bit_cast(_Float16, (unsigned short)(lo & 0xFFFF));
    float h1 = (float)__builtin_bit_cast(_Float16, (unsigned short)(lo >> 16));
    acc += h0 * W_lat[(size_t)lc * 512 + 2 * j] + h1 * W_lat[(size_t)lc * 512 + 2 * j + 1];
  }
  Z[(size_t)b * 256 + lc] = acc + b_lat[lc];
}

__global__ __launch_bounds__(256) void zx_kernel(const float* __restrict__ Z,
                                                 const float* __restrict__ W_ihd,
                                                 const float* __restrict__ b_d,
                                                 float* __restrict__ ZX) {
  int o = blockIdx.x * 256 + threadIdx.x;
  int b = o >> 11, gc = o & 2047;
  const F4* zp = (const F4*)(Z + (size_t)b * 256);
  const F4* wp = (const F4*)(W_ihd + (size_t)gc * 256);
  float acc = 0.f;
  for (int k4 = 0; k4 < 64; k4++) {
    F4 z = zp[k4], wv = wp[k4];
    acc += z[0] * wv[0] + z[1] * wv[1] + z[2] * wv[2] + z[3] * wv[3];
  }
  ZX[o] = acc + b_d[gc];
}

// ------------------------- persistent decoder -------------------------
__global__ __launch_bounds__(256, 1) void dec_persist(
    const uint4* __restrict__ Wf, const uint4* __restrict__ WfO,
    u64* __restrict__ Ring, const float* __restrict__ ZX,
    const float* __restrict__ b_out, float* __restrict__ out,
    const int* __restrict__ lengths) {
  const int tid = threadIdx.x;
  const int l = tid & 63, g = tid >> 6;
  const int bi = (int)blockIdx.x & 7, w = (int)blockIdx.x >> 3;
  __shared__ u32x4 Hlds[1024];
  __shared__ float gl[4][16][17];
  __shared__ unsigned short hst[16][16];

  uint4 wb[16], wo[16];
#pragma unroll
  for (int k = 0; k < 16; k++) {
    wb[k] = Wf[(size_t)w * 4096 + (g * 16 + k) * 64 + l];
    wo[k] = WfO[(size_t)g * 1024 + k * 64 + l];
    PIN4(wb[k]); PIN4(wo[k]);
  }

  const int row = tid >> 4, col = tid & 15;
  const int b = bi * 16 + row;
  const int len = lengths[b];
  const int lenA = lengths[bi * 16 + (l & 15)];
  const float bo = b_out[g * 16 + (l & 15)];
  const float zr0 = ZX[(size_t)b * 2048 + w * 16 + col];
  const float zr1 = ZX[(size_t)b * 2048 + 512 + w * 16 + col];
  const float zr2 = ZX[(size_t)b * 2048 + 1024 + w * 16 + col];
  const float zr3 = ZX[(size_t)b * 2048 + 1536 + w * 16 + col];
  float cst = 0.f, hreg = 0.f;
  const int srow = tid >> 4, scb = tid & 15;
  u64* ringT = Ring + (size_t)bi * (4 * 16 * 256);
  const int ar = l & 15, swz = ar & 7, r0 = (l >> 4) * 4;

  for (int t = 0; t <= NT; t++) {
    if (t == NT && w != 31) break;
    if (t > 0) {
      STAGE_H(ringT, t);
      __syncthreads();
    }
    if (t < NT) {
      F4 acc0 = {0.f, 0.f, 0.f, 0.f}, acc1 = {0.f, 0.f, 0.f, 0.f};
      if (t > 0) {
#pragma unroll
        for (int k = 0; k < 16; k += 2) {
          u32x4 a0 = Hlds[ar * 64 + (((l >> 4) + 4 * k) ^ swz)];
          u32x4 a1 = Hlds[ar * 64 + (((l >> 4) + 4 * (k + 1)) ^ swz)];
          acc0 = __builtin_amdgcn_mfma_f32_16x16x32_f16(
              __builtin_bit_cast(half8, a0), __builtin_bit_cast(half8, wb[k]), acc0, 0, 0, 0);
          acc1 = __builtin_amdgcn_mfma_f32_16x16x32_f16(
              __builtin_bit_cast(half8, a1), __builtin_bit_cast(half8, wb[k + 1]), acc1, 0, 0, 0);
        }
      }
      F4 acc = acc0 + acc1;
#pragma unroll
      for (int r = 0; r < 4; r++) gl[g][r0 + r][ar] = acc[r];
      __syncthreads();

      float hv;
      if (t < len) {
        float gi = gl[0][row][col] + zr0;
        float gf = gl[1][row][col] + zr1;
        float gg = gl[2][row][col] + zr2;
        float go = gl[3][row][col] + zr3;
        float i = sigm(gi), f = sigm(gf), gz = tanh_(gg), o = sigm(go);
        cst = f * cst + i * gz;
        hv = o * tanh_(cst);
      } else {
        hv = hreg;
      }
      hreg = hv;
      hst[row][col] = __builtin_bit_cast(unsigned short, (_Float16)hv);
      __syncthreads();

      if (tid < 128) {
        int pr = tid >> 3, pk = tid & 7;
        u32 lo = (u32)hst[pr][2 * pk] | ((u32)hst[pr][2 * pk + 1] << 16);
        u64 vv = ((u64)(u32)(t + 1) << 32) | lo;
        __hip_atomic_store(ringT + ((size_t)((t + 1) & 3) * 16 + pr) * 256 + w * 8 + pk,
                           vv, __ATOMIC_RELAXED, __HIP_MEMORY_SCOPE_AGENT);
      }
    }
    // fused output projection for time t-1 (overlaps others' next-step poll)
    if (t > 0 && w == ((t - 1) & 31)) {
      bool ma = (t - 1) < lenA;
      F4 oa0 = {0.f, 0.f, 0.f, 0.f}, oa1 = {0.f, 0.f, 0.f, 0.f};
      u32x4 zer = {0u, 0u, 0u, 0u};
#pragma unroll
      for (int k = 0; k < 16; k += 2) {
        u32x4 a0 = ma ? Hlds[ar * 64 + (((l >> 4) + 4 * k) ^ swz)] : zer;
        u32x4 a1 = ma ? Hlds[ar * 64 + (((l >> 4) + 4 * (k + 1)) ^ swz)] : zer;
        oa0 = __builtin_amdgcn_mfma_f32_16x16x32_f16(
            __builtin_bit_cast(half8, a0), __builtin_bit_cast(half8, wo[k]), oa0, 0, 0, 0);
        oa1 = __builtin_amdgcn_mfma_f32_16x16x32_f16(
            __builtin_bit_cast(half8, a1), __builtin_bit_cast(half8, wo[k + 1]), oa1, 0, 0, 0);
      }
      F4 oa = oa0 + oa1;
#pragma unroll
      for (int r = 0; r < 4; r++)
        out[((size_t)(bi * 16 + r0 + r) * NT + (t - 1)) * 64 + g * 16 + (l & 15)] = oa[r] + bo;
    }
  }
}

// ------------------------- host -------------------------
extern "C" void kernel_launch(void* const* d_in, const int* in_sizes, int n_in,
                              void* d_out, int out_size, void* d_ws, size_t ws_size,
                              hipStream_t stream) {
  const float* x      = (const float*)d_in[0];
  const int* lengths  = (const int*)d_in[1];
  const float* W_ih_e = (const float*)d_in[2];
  const float* W_hh_e = (const float*)d_in[3];
  const float* b_e    = (const float*)d_in[4];
  const float* W_lat  = (const float*)d_in[5];
  const float* b_lat  = (const float*)d_in[6];
  const float* W_ih_d = (const float*)d_in[7];
  const float* W_hh_d = (const float*)d_in[8];
  const float* b_d    = (const float*)d_in[9];
  const float* W_out  = (const float*)d_in[10];
  const float* b_out  = (const float*)d_in[11];
  float* out = (float*)d_out;
  char* ws = (char*)d_ws;

  half8* WfE = (half8*)(ws + OFF_WFE);
  half8* WfD = (half8*)(ws + OFF_WFD);
  half8* WfX = (half8*)(ws + OFF_WFX);
  half8* WfO = (half8*)(ws + OFF_WFO);
  half8* Xf  = (half8*)(ws + OFF_XF);
  u64* RingE = (u64*)(ws + OFF_RE);
  u64* RingD = (u64*)(ws + OFF_RD);
  float* Z  = (float*)(ws + OFF_Z);
  float* ZX = (float*)(ws + OFF_ZX);

  hipMemsetAsync(RingE, 0, 2u << 20, stream);  // both rings (contiguous)
  setup_kernel<<<3152, 256, 0, stream>>>(x, W_hh_e, W_ih_e, W_hh_d, W_out,
                                         WfE, WfX, WfD, WfO, Xf);

  enc_persist<<<256, 256, 0, stream>>>((const uint4*)WfE, (const uint4*)WfX,
                                       (const uint4*)Xf, RingE, b_e, lengths);
  z_kernel<<<128, 256, 0, stream>>>(RingE, W_lat, b_lat, Z);
  zx_kernel<<<1024, 256, 0, stream>>>(Z, W_ih_d, b_d, ZX);
  dec_persist<<<256, 256, 0, stream>>>((const uint4*)WfD, (const uint4*)WfO,
                                       RingD, ZX, b_out, out, lengths);
}